// Round 6
// baseline (195.866 us; speedup 1.0000x reference)
//
#include <hip/hip_runtime.h>
#include <stdint.h>

typedef _Float16 v8h __attribute__((ext_vector_type(8)));
typedef _Float16 v2h __attribute__((ext_vector_type(2)));
typedef float v4f __attribute__((ext_vector_type(4)));
typedef float v16f __attribute__((ext_vector_type(16)));

#define NPTS 2048
#define BATCH 16
#define KNN 20
#define PAIRS (NPTS * KNN)   // 40960 per batch

// ---------- helpers ----------
// R6/R7: fp16 pair op: 2 packed ops (v_pk_add_f16 + v_pk_max_f16).
__device__ __forceinline__ unsigned pair_relu_h2(unsigned pu, unsigned qu) {
  v2h a = *(const v2h*)&pu;
  v2h b = *(const v2h*)&qu;
  v2h s = a + b;                                   // v_pk_add_f16
  v2h z = {(_Float16)0.f, (_Float16)0.f};
  v2h r = __builtin_elementwise_max(s, z);         // v_pk_max_f16 (relu)
  return *(const unsigned*)&r;
}
// clang fuses fmaxf(fmaxf(a,b),c) -> v_max3_f32 (single VALU op)
__device__ __forceinline__ float fmax3(float a, float b, float c) {
  return fmaxf(fmaxf(a, b), c);
}

// ---------- K0: fold M2a = W2*W1a, M2b = W2*(W1b-W1a); zero H ----------
__global__ void prep_kernel(const float* __restrict__ W1, const float* __restrict__ W2,
                            float* __restrict__ M2a, float* __restrict__ M2b,
                            int* __restrict__ H) {
  if (blockIdx.x == 0 && threadIdx.x < 128) {
    int o = threadIdx.x;
    float a0 = 0, a1 = 0, a2 = 0, b0 = 0, b1 = 0, b2 = 0;
    for (int i = 0; i < 64; ++i) {
      float w2 = W2[o * 64 + i];
      const float* w1r = W1 + i * 6;
      a0 += w2 * w1r[0]; a1 += w2 * w1r[1]; a2 += w2 * w1r[2];
      b0 += w2 * (w1r[3] - w1r[0]); b1 += w2 * (w1r[4] - w1r[1]); b2 += w2 * (w1r[5] - w1r[2]);
    }
    M2a[o * 3 + 0] = a0; M2a[o * 3 + 1] = a1; M2a[o * 3 + 2] = a2;
    M2b[o * 3 + 0] = b0; M2b[o * 3 + 1] = b1; M2b[o * 3 + 2] = b2;
  }
  int g = blockIdx.x * 128 + threadIdx.x;
  if (g < BATCH * 256) H[g] = 0;
}

// ---------- K1: p[b][j][o] = M2a[o]·x_j ; q likewise (fp16, packed pairs) ----------
__global__ __launch_bounds__(64) void pq_kernel(const float* __restrict__ x,
                                                const float* __restrict__ M2a,
                                                const float* __restrict__ M2b,
                                                unsigned short* __restrict__ p,
                                                unsigned short* __restrict__ q) {
  int b = blockIdx.x >> 6;
  int j0 = (blockIdx.x & 63) << 5;
  int t = threadIdx.x;                 // 0..63 -> channels 2t, 2t+1
  int o0 = t * 2;
  float a00 = M2a[o0 * 3 + 0], a01 = M2a[o0 * 3 + 1], a02 = M2a[o0 * 3 + 2];
  float a10 = M2a[o0 * 3 + 3], a11 = M2a[o0 * 3 + 4], a12 = M2a[o0 * 3 + 5];
  float b00 = M2b[o0 * 3 + 0], b01 = M2b[o0 * 3 + 1], b02 = M2b[o0 * 3 + 2];
  float b10 = M2b[o0 * 3 + 3], b11 = M2b[o0 * 3 + 4], b12 = M2b[o0 * 3 + 5];
  const float* xb = x + b * 3 * NPTS;
  unsigned* pw = (unsigned*)p;
  unsigned* qw = (unsigned*)q;
  for (int jj = 0; jj < 32; ++jj) {
    int j = j0 + jj;
    float x0 = xb[j], x1 = xb[NPTS + j], x2 = xb[2 * NPTS + j];
    float p0 = a00 * x0 + a01 * x1 + a02 * x2;
    float p1 = a10 * x0 + a11 * x1 + a12 * x2;
    float q0 = b00 * x0 + b01 * x1 + b02 * x2;
    float q1 = b10 * x0 + b11 * x1 + b12 * x2;
    size_t base = ((size_t)(b * NPTS + j)) * 64 + t;   // dword index
    auto hp = __builtin_amdgcn_cvt_pkrtz(p0, p1);      // v_cvt_pkrtz_f16_f32
    auto hq = __builtin_amdgcn_cvt_pkrtz(q0, q1);
    pw[base] = *(const unsigned*)&hp;
    qw[base] = *(const unsigned*)&hq;
  }
}

// ---------- K2: exact 20-NN ----------
// R10: knn was the top dispatch (53us, VALUBusy 76%, MfmaUtil 0) -> pure
// VALU-inst-count bound. Cuts:
//  (a) norm trick: stage (x,y,z,|x|^2) float4; d' = nrm - 2 q.x via 3 FMA
//      (was 3 sub + 3 fma); 1 ds_read_b128 w/ static offset (was 3 b32).
//      d' = |x-q|^2 - |q|^2 (order-preserving; can be negative -> sort key
//      is float_as_uint(d'+64), monotone since d' > -64 for this data).
//  (b) 8 queries/wave + 512-thr blocks: halves shared overhead & staging;
//      grid 512 = exactly 2 blocks/CU, LDS 64KB -> occupancy 35->50%.
//  (c) 64 cand slots (E[cnt]~23, P(>64) ~6 sigma): single-key rank-count.
//  tau inflation sign-safe for negative d': t + |t|*4e-6 + 1e-6.
__global__ __launch_bounds__(512, 4) void knn_kernel(const float* __restrict__ x,
                                                     int* __restrict__ idxOut) {
  __shared__ float4 pts[NPTS];                    // 32 KB (x,y,z,|.|^2)
  __shared__ unsigned long long cand[8][8][64];   // 32 KB, wave-private
  int b = blockIdx.x >> 5;
  int qblk = blockIdx.x & 31;
  const float* xb = x + b * 3 * NPTS;
  for (int i = threadIdx.x; i < NPTS; i += 512) {
    float X = xb[i], Y = xb[NPTS + i], Z = xb[2 * NPTS + i];
    pts[i] = make_float4(X, Y, Z, X * X + Y * Y + Z * Z);
  }
  __syncthreads();
  int wid = threadIdx.x >> 6, lane = threadIdx.x & 63;
  int qbase = qblk * 64 + wid * 8;                // 8 queries per wave

  float m2x[8], m2y[8], m2z[8], mn[8];
#pragma unroll
  for (int g = 0; g < 8; ++g) {
    float4 qp = pts[qbase + g];                   // broadcast read
    m2x[g] = -2.f * qp.x; m2y[g] = -2.f * qp.y; m2z[g] = -2.f * qp.z;
    mn[g] = 1e30f;
  }

  // pass 1: per-lane min over its 32 points, all 8 queries share the load
  for (int s = 0; s < 32; ++s) {
    float4 P = pts[s * 64 + lane];
#pragma unroll
    for (int g = 0; g < 8; ++g) {
      float d = fmaf(m2x[g], P.x, fmaf(m2y[g], P.y, fmaf(m2z[g], P.z, P.w)));
      mn[g] = fminf(mn[g], d);
    }
  }

  // tau[g] = 20th-smallest lane-min (upper bound on d'_(20)), inflated
  float tau[8];
#pragma unroll
  for (int g = 0; g < 8; ++g) {
    float v = mn[g];
    for (int k = 2; k <= 64; k <<= 1) {
      for (int j = k >> 1; j > 0; j >>= 1) {
        float o = __shfl_xor(v, j);
        bool low = (lane & j) == 0;
        bool up = (lane & k) == 0;
        v = (low == up) ? fminf(v, o) : fmaxf(v, o);
      }
    }
    float t = __shfl(v, 19);
    tau[g] = t + fabsf(t) * 4e-6f + 1e-6f;
  }

  // pass 2: recompute, ballot-compact candidates per query
  int cnt[8] = {0, 0, 0, 0, 0, 0, 0, 0};
  for (int s = 0; s < 32; ++s) {
    int i = s * 64 + lane;
    float4 P = pts[i];
#pragma unroll
    for (int g = 0; g < 8; ++g) {
      float d = fmaf(m2x[g], P.x, fmaf(m2y[g], P.y, fmaf(m2z[g], P.z, P.w)));
      bool take = d <= tau[g];
      unsigned long long mb = __ballot(take);
      if (take) {
        int pos = cnt[g] + __popcll(mb & ((1ull << lane) - 1ull));
        if (pos < 64) {
          unsigned kd = __float_as_uint(d + 64.f);   // d > -64: monotone key
          cand[wid][g][pos] = (((unsigned long long)kd) << 32) | (unsigned)i;
        }
      }
      cnt[g] += __popcll(mb);
    }
  }
  // cand written & read by the same wave: no __syncthreads needed.

  // rank-count select: broadcast reads (same addr all lanes = free).
  // Keys unique (index tiebreak) -> exact ranks; >=20 candidates guaranteed
  // (>=20 lanes have lane-min <= tau, each contributes >=1).
#pragma unroll
  for (int g = 0; g < 8; ++g) {
    int nc = cnt[g] < 64 ? cnt[g] : 64;
    unsigned long long k0 = (lane < nc) ? cand[wid][g][lane] : ~0ull;
    int r0 = 0;
    for (int i = 0; i < nc; ++i) r0 += (cand[wid][g][i] < k0) ? 1 : 0;
    long long obase = ((long long)b * NPTS + qbase + g) * KNN;
    if (lane < nc && r0 < KNN) idxOut[obase + r0] = (int)(k0 & 0xffffffffu);
  }
}

// ---------- K3: h3 = relu(W3 · relu(p_j+q_n)) via MFMA, fused max-reduce ----------
// R11: latency-bound at 25% occupancy (Mfma 33 / VALU 28 / LDS ~44, nothing
// saturated; 8-deep dependent MFMA chains + barrier per iter with only 2
// waves/SIMD to cover the bubbles). Changes:
//  (a) 4 blocks/CU: grid 48->64 w-blocks (stride 64 -> 20 EXACT iters, all
//      prefetch branches uniform), __launch_bounds__(256,4). 16 waves/CU.
//  (b) max-reduce via v_max3_f32 triples: 32 -> 16 VALU ops/iter.
// R9 (kept): batch->XCD pinning (b = blockIdx&15); 2 ntiles per a[kk] read;
// idx prefetched 2 tiles ahead, p/q 1 ahead.
__global__ __launch_bounds__(256, 4) void gemm_max_kernel(
    const unsigned short* __restrict__ p, const unsigned short* __restrict__ q,
    const int* __restrict__ idx, const float* __restrict__ W3, int* __restrict__ H) {
  __shared__ __align__(16) unsigned short h2s[2][32 * 128];  // 16 KB double-buffered

  int b = blockIdx.x & 15;
  int w = blockIdx.x >> 4;            // 0..63
  int t = threadIdx.x;                // 0..255
  int lane = t & 63, wid = t >> 6;    // 4 waves
  int col = lane & 31, hi = lane >> 5;

  // B fragments: wave owns channels [wid*64, wid*64+64) as 2 ntiles.
  // B[k][n]: lane holds n = ntl-base + col, k = kk*16 + hi*8 + j.
  v8h bfr0[8], bfr1[8];
#pragma unroll
  for (int kk = 0; kk < 8; ++kk) {
    const float* s0 = W3 + (size_t)(wid * 64 + col) * 128 + kk * 16 + hi * 8;
    const float* s1 = s0 + 32 * 128;
    v8h f0, f1;
#pragma unroll
    for (int jj = 0; jj < 8; ++jj) { f0[jj] = (_Float16)s0[jj]; f1[jj] = (_Float16)s1[jj]; }
    bfr0[kk] = f0; bfr1[kk] = f1;
  }

  const unsigned short* pB = p + (size_t)b * NPTS * 128;
  const unsigned short* qB = q + (size_t)b * NPTS * 128;
  const int* idxB = idx + (size_t)b * PAIRS;

  int pm = t >> 3;        // pair-in-tile 0..31
  int c2 = t & 7;         // covers 16B units 2*c2, 2*c2+1 (32B of the row)
  // swizzled LDS store offsets (shorts): unit u -> u ^ (row&7)
  int st0 = pm * 128 + (((c2 * 2) ^ (pm & 7)) * 8);
  int st1 = pm * 128 + (((c2 * 2 + 1) ^ (pm & 7)) * 8);

  const int NT = PAIRS / 32;          // 1280 tiles/batch; stride 64 -> 20 iters

  // prologue: loads for tile w; idx one tile ahead
  uint4 P0, P1, Q0, Q1;
  int jn = 0;
  {
    int pr = w * 32 + pm;
    int j = idxB[pr] & (NPTS - 1);
    int n = pr / 20;
    P0 = *(const uint4*)(pB + (size_t)j * 128 + c2 * 16);
    P1 = *(const uint4*)(pB + (size_t)j * 128 + c2 * 16 + 8);
    Q0 = *(const uint4*)(qB + (size_t)n * 128 + c2 * 16);
    Q1 = *(const uint4*)(qB + (size_t)n * 128 + c2 * 16 + 8);
    int T1 = w + 64;
    if (T1 < NT) jn = idxB[T1 * 32 + pm];
  }

  float vmx0 = 0.f, vmx1 = 0.f;
  int buf = 0;
  for (int T = w; T < NT; T += 64) {
    // stage h2 tile (32 pairs x 128 ch, fp16) from prefetched regs
    uint4 R0, R1;
    R0.x = pair_relu_h2(P0.x, Q0.x); R0.y = pair_relu_h2(P0.y, Q0.y);
    R0.z = pair_relu_h2(P0.z, Q0.z); R0.w = pair_relu_h2(P0.w, Q0.w);
    R1.x = pair_relu_h2(P1.x, Q1.x); R1.y = pair_relu_h2(P1.y, Q1.y);
    R1.z = pair_relu_h2(P1.z, Q1.z); R1.w = pair_relu_h2(P1.w, Q1.w);
    *(uint4*)&h2s[buf][st0] = R0;
    *(uint4*)&h2s[buf][st1] = R1;
    __syncthreads();   // one barrier/iter: dbuf covers the read-vs-overwrite hazard

    // prefetch tile T+64 (p-row from jn loaded last iter); idx for T+128
    int Tn = T + 64;
    if (Tn < NT) {
      int prn = Tn * 32 + pm;
      int j = jn & (NPTS - 1);
      int n = prn / 20;
      P0 = *(const uint4*)(pB + (size_t)j * 128 + c2 * 16);
      P1 = *(const uint4*)(pB + (size_t)j * 128 + c2 * 16 + 8);
      Q0 = *(const uint4*)(qB + (size_t)n * 128 + c2 * 16);
      Q1 = *(const uint4*)(qB + (size_t)n * 128 + c2 * 16 + 8);
      int T2 = T + 128;
      if (T2 < NT) jn = idxB[T2 * 32 + pm];
    }

    // compute: one a[kk] read feeds both ntiles (16 MFMA per 8 ds_read)
    v16f acc0 = {0.f}, acc1 = {0.f};
#pragma unroll
    for (int kk = 0; kk < 8; ++kk) {
      v8h a = *(const v8h*)&h2s[buf][col * 128 + (((kk * 2 + hi) ^ (col & 7)) * 8)];
      acc0 = __builtin_amdgcn_mfma_f32_32x32x16_f16(a, bfr0[kk], acc0, 0, 0, 0);
      acc1 = __builtin_amdgcn_mfma_f32_32x32x16_f16(a, bfr1[kk], acc1, 0, 0, 0);
    }
    // relu folds into max (vmx starts at 0); v_max3 triples: 8 ops per acc
    {
      float m0 = fmax3(acc0[0], acc0[1], acc0[2]);
      float m1 = fmax3(acc0[3], acc0[4], acc0[5]);
      float m2 = fmax3(acc0[6], acc0[7], acc0[8]);
      float m3 = fmax3(acc0[9], acc0[10], acc0[11]);
      float m4 = fmax3(acc0[12], acc0[13], acc0[14]);
      vmx0 = fmax3(fmax3(m0, m1, m2), fmax3(m3, m4, acc0[15]), vmx0);
      float n0 = fmax3(acc1[0], acc1[1], acc1[2]);
      float n1 = fmax3(acc1[3], acc1[4], acc1[5]);
      float n2 = fmax3(acc1[6], acc1[7], acc1[8]);
      float n3 = fmax3(acc1[9], acc1[10], acc1[11]);
      float n4 = fmax3(acc1[12], acc1[13], acc1[14]);
      vmx1 = fmax3(fmax3(n0, n1, n2), fmax3(n3, n4, acc1[15]), vmx1);
    }
    buf ^= 1;
  }

  // lanes l and l^32 hold the same channel (complementary rows): reduce, write
  float v0 = fmaxf(vmx0, __shfl_xor(vmx0, 32));
  float v1 = fmaxf(vmx1, __shfl_xor(vmx1, 32));
  if (hi == 0) {
    atomicMax(&H[b * 256 + wid * 64 + col], __float_as_int(v0));
    atomicMax(&H[b * 256 + wid * 64 + 32 + col], __float_as_int(v1));
  }
}

// ---------- K4: out = H @ fc_w^T + fc_b (one wave per output element) ----------
__global__ __launch_bounds__(64) void fc_kernel(const int* __restrict__ Hi,
                                                const float* __restrict__ fcw,
                                                const float* __restrict__ fcb,
                                                float* __restrict__ out) {
  int b = blockIdx.x / 10, r = blockIdx.x % 10;
  int lane = threadIdx.x;
  const float* Hb = (const float*)Hi + b * 256;
  float s = 0.f;
#pragma unroll
  for (int c = lane; c < 256; c += 64) s += Hb[c] * fcw[r * 256 + c];
#pragma unroll
  for (int m = 32; m > 0; m >>= 1) s += __shfl_xor(s, m);
  if (lane == 0) out[b * 10 + r] = s + fcb[r];
}

// ---------- launch ----------
extern "C" void kernel_launch(void* const* d_in, const int* in_sizes, int n_in,
                              void* d_out, int out_size, void* d_ws, size_t ws_size,
                              hipStream_t stream) {
  const float* x   = (const float*)d_in[0];
  const float* W1  = (const float*)d_in[1];
  const float* W2  = (const float*)d_in[2];
  const float* W3  = (const float*)d_in[3];
  const float* fcw = (const float*)d_in[4];
  const float* fcb = (const float*)d_in[5];
  float* out = (float*)d_out;
  char* ws = (char*)d_ws;

  // workspace layout (needs ~20 MB)
  float* M2a = (float*)(ws + 0);            // 1536 B
  float* M2b = (float*)(ws + 1536);         // 1536 B
  int* H     = (int*)(ws + 4096);           // 16 KB (16x256 f32-as-int)
  int* idx   = (int*)(ws + 24576);          // 2.62 MB
  unsigned short* p = (unsigned short*)(ws + 3145728);   // 8.39 MB fp16
  unsigned short* q = (unsigned short*)(ws + 12582912);  // 8.39 MB fp16

  prep_kernel<<<32, 128, 0, stream>>>(W1, W2, M2a, M2b, H);
  pq_kernel<<<BATCH * 64, 64, 0, stream>>>(x, M2a, M2b, p, q);
  knn_kernel<<<BATCH * 32, 512, 0, stream>>>(x, idx);
  gemm_max_kernel<<<BATCH * 64, 256, 0, stream>>>(p, q, idx, W3, H);
  fc_kernel<<<BATCH * 10, 64, 0, stream>>>(H, fcw, fcb, out);
}

// Round 7
// 173.124 us; speedup vs baseline: 1.1314x; 1.1314x over previous
//
#include <hip/hip_runtime.h>
#include <stdint.h>

typedef _Float16 v8h __attribute__((ext_vector_type(8)));
typedef _Float16 v2h __attribute__((ext_vector_type(2)));
typedef float v4f __attribute__((ext_vector_type(4)));
typedef float v16f __attribute__((ext_vector_type(16)));

#define NPTS 2048
#define BATCH 16
#define KNN 20
#define PAIRS (NPTS * KNN)   // 40960 per batch

// ---------- helpers ----------
// R6/R7: fp16 pair op: 2 packed ops (v_pk_add_f16 + v_pk_max_f16).
__device__ __forceinline__ unsigned pair_relu_h2(unsigned pu, unsigned qu) {
  v2h a = *(const v2h*)&pu;
  v2h b = *(const v2h*)&qu;
  v2h s = a + b;                                   // v_pk_add_f16
  v2h z = {(_Float16)0.f, (_Float16)0.f};
  v2h r = __builtin_elementwise_max(s, z);         // v_pk_max_f16 (relu)
  return *(const unsigned*)&r;
}
// clang fuses fmaxf(fmaxf(a,b),c) -> v_max3_f32 (single VALU op)
__device__ __forceinline__ float fmax3(float a, float b, float c) {
  return fmaxf(fmaxf(a, b), c);
}

// ---------- K0: fold M2a = W2*W1a, M2b = W2*(W1b-W1a); zero H ----------
__global__ void prep_kernel(const float* __restrict__ W1, const float* __restrict__ W2,
                            float* __restrict__ M2a, float* __restrict__ M2b,
                            int* __restrict__ H) {
  if (blockIdx.x == 0 && threadIdx.x < 128) {
    int o = threadIdx.x;
    float a0 = 0, a1 = 0, a2 = 0, b0 = 0, b1 = 0, b2 = 0;
    for (int i = 0; i < 64; ++i) {
      float w2 = W2[o * 64 + i];
      const float* w1r = W1 + i * 6;
      a0 += w2 * w1r[0]; a1 += w2 * w1r[1]; a2 += w2 * w1r[2];
      b0 += w2 * (w1r[3] - w1r[0]); b1 += w2 * (w1r[4] - w1r[1]); b2 += w2 * (w1r[5] - w1r[2]);
    }
    M2a[o * 3 + 0] = a0; M2a[o * 3 + 1] = a1; M2a[o * 3 + 2] = a2;
    M2b[o * 3 + 0] = b0; M2b[o * 3 + 1] = b1; M2b[o * 3 + 2] = b2;
  }
  int g = blockIdx.x * 128 + threadIdx.x;
  if (g < BATCH * 256) H[g] = 0;
}

// ---------- K1: p[b][j][o] = M2a[o]·x_j ; q likewise (fp16, packed pairs) ----------
__global__ __launch_bounds__(64) void pq_kernel(const float* __restrict__ x,
                                                const float* __restrict__ M2a,
                                                const float* __restrict__ M2b,
                                                unsigned short* __restrict__ p,
                                                unsigned short* __restrict__ q) {
  int b = blockIdx.x >> 6;
  int j0 = (blockIdx.x & 63) << 5;
  int t = threadIdx.x;                 // 0..63 -> channels 2t, 2t+1
  int o0 = t * 2;
  float a00 = M2a[o0 * 3 + 0], a01 = M2a[o0 * 3 + 1], a02 = M2a[o0 * 3 + 2];
  float a10 = M2a[o0 * 3 + 3], a11 = M2a[o0 * 3 + 4], a12 = M2a[o0 * 3 + 5];
  float b00 = M2b[o0 * 3 + 0], b01 = M2b[o0 * 3 + 1], b02 = M2b[o0 * 3 + 2];
  float b10 = M2b[o0 * 3 + 3], b11 = M2b[o0 * 3 + 4], b12 = M2b[o0 * 3 + 5];
  const float* xb = x + b * 3 * NPTS;
  unsigned* pw = (unsigned*)p;
  unsigned* qw = (unsigned*)q;
  for (int jj = 0; jj < 32; ++jj) {
    int j = j0 + jj;
    float x0 = xb[j], x1 = xb[NPTS + j], x2 = xb[2 * NPTS + j];
    float p0 = a00 * x0 + a01 * x1 + a02 * x2;
    float p1 = a10 * x0 + a11 * x1 + a12 * x2;
    float q0 = b00 * x0 + b01 * x1 + b02 * x2;
    float q1 = b10 * x0 + b11 * x1 + b12 * x2;
    size_t base = ((size_t)(b * NPTS + j)) * 64 + t;   // dword index
    auto hp = __builtin_amdgcn_cvt_pkrtz(p0, p1);      // v_cvt_pkrtz_f16_f32
    auto hq = __builtin_amdgcn_cvt_pkrtz(q0, q1);
    pw[base] = *(const unsigned*)&hp;
    qw[base] = *(const unsigned*)&hq;
  }
}

// ---------- K2: exact 20-NN ----------
// R10: knn was the top dispatch (53us, VALUBusy 76%, MfmaUtil 0) -> pure
// VALU-inst-count bound. Cuts:
//  (a) norm trick: stage (x,y,z,|x|^2) float4; d' = nrm - 2 q.x via 3 FMA
//      (was 3 sub + 3 fma); 1 ds_read_b128 w/ static offset (was 3 b32).
//      d' = |x-q|^2 - |q|^2 (order-preserving; can be negative -> sort key
//      is float_as_uint(d'+64), monotone since d' > -64 for this data).
//  (b) 8 queries/wave + 512-thr blocks: halves shared overhead & staging;
//      grid 512 = exactly 2 blocks/CU, LDS 64KB -> occupancy 35->50%.
//  (c) 64 cand slots (E[cnt]~23, P(>64) ~6 sigma): single-key rank-count.
//  tau inflation sign-safe for negative d': t + |t|*4e-6 + 1e-6.
__global__ __launch_bounds__(512, 4) void knn_kernel(const float* __restrict__ x,
                                                     int* __restrict__ idxOut) {
  __shared__ float4 pts[NPTS];                    // 32 KB (x,y,z,|.|^2)
  __shared__ unsigned long long cand[8][8][64];   // 32 KB, wave-private
  int b = blockIdx.x >> 5;
  int qblk = blockIdx.x & 31;
  const float* xb = x + b * 3 * NPTS;
  for (int i = threadIdx.x; i < NPTS; i += 512) {
    float X = xb[i], Y = xb[NPTS + i], Z = xb[2 * NPTS + i];
    pts[i] = make_float4(X, Y, Z, X * X + Y * Y + Z * Z);
  }
  __syncthreads();
  int wid = threadIdx.x >> 6, lane = threadIdx.x & 63;
  int qbase = qblk * 64 + wid * 8;                // 8 queries per wave

  float m2x[8], m2y[8], m2z[8], mn[8];
#pragma unroll
  for (int g = 0; g < 8; ++g) {
    float4 qp = pts[qbase + g];                   // broadcast read
    m2x[g] = -2.f * qp.x; m2y[g] = -2.f * qp.y; m2z[g] = -2.f * qp.z;
    mn[g] = 1e30f;
  }

  // pass 1: per-lane min over its 32 points, all 8 queries share the load
  for (int s = 0; s < 32; ++s) {
    float4 P = pts[s * 64 + lane];
#pragma unroll
    for (int g = 0; g < 8; ++g) {
      float d = fmaf(m2x[g], P.x, fmaf(m2y[g], P.y, fmaf(m2z[g], P.z, P.w)));
      mn[g] = fminf(mn[g], d);
    }
  }

  // tau[g] = 20th-smallest lane-min (upper bound on d'_(20)), inflated
  float tau[8];
#pragma unroll
  for (int g = 0; g < 8; ++g) {
    float v = mn[g];
    for (int k = 2; k <= 64; k <<= 1) {
      for (int j = k >> 1; j > 0; j >>= 1) {
        float o = __shfl_xor(v, j);
        bool low = (lane & j) == 0;
        bool up = (lane & k) == 0;
        v = (low == up) ? fminf(v, o) : fmaxf(v, o);
      }
    }
    float t = __shfl(v, 19);
    tau[g] = t + fabsf(t) * 4e-6f + 1e-6f;
  }

  // pass 2: recompute, ballot-compact candidates per query
  int cnt[8] = {0, 0, 0, 0, 0, 0, 0, 0};
  for (int s = 0; s < 32; ++s) {
    int i = s * 64 + lane;
    float4 P = pts[i];
#pragma unroll
    for (int g = 0; g < 8; ++g) {
      float d = fmaf(m2x[g], P.x, fmaf(m2y[g], P.y, fmaf(m2z[g], P.z, P.w)));
      bool take = d <= tau[g];
      unsigned long long mb = __ballot(take);
      if (take) {
        int pos = cnt[g] + __popcll(mb & ((1ull << lane) - 1ull));
        if (pos < 64) {
          unsigned kd = __float_as_uint(d + 64.f);   // d > -64: monotone key
          cand[wid][g][pos] = (((unsigned long long)kd) << 32) | (unsigned)i;
        }
      }
      cnt[g] += __popcll(mb);
    }
  }
  // cand written & read by the same wave: no __syncthreads needed.

  // rank-count select: broadcast reads (same addr all lanes = free).
  // Keys unique (index tiebreak) -> exact ranks; >=20 candidates guaranteed
  // (>=20 lanes have lane-min <= tau, each contributes >=1).
#pragma unroll
  for (int g = 0; g < 8; ++g) {
    int nc = cnt[g] < 64 ? cnt[g] : 64;
    unsigned long long k0 = (lane < nc) ? cand[wid][g][lane] : ~0ull;
    int r0 = 0;
    for (int i = 0; i < nc; ++i) r0 += (cand[wid][g][i] < k0) ? 1 : 0;
    long long obase = ((long long)b * NPTS + qbase + g) * KNN;
    if (lane < nc && r0 < KNN) idxOut[obase + r0] = (int)(k0 & 0xffffffffu);
  }
}

// ---------- K3: h3 = relu(W3 · relu(p_j+q_n)) via MFMA, fused max-reduce ----------
// R12 post-R11-spill: NEVER cap VGPRs below natural footprint (R11's
// (256,4) forced 64 VGPR -> acc/bfr spilled to scratch -> 48MB HBM writes,
// 2x regression). Instead halve per-MFMA overhead structurally:
//   M=64 pair tile, 512-thr/8-wave blocks. Waves 0-3 do rows 0-31,
//   waves 4-7 rows 32-63; each wave 2 ntiles (64 ch). Per unit MFMA work:
//   staging VALU, gathers, barriers all HALVED vs R10 (same per-thread
//   cost, 2x tile). LDS read:MFMA ratio unchanged, swizzle conflict-free.
//   (512,2): VGPR cap 256 -> spill impossible; 20 exact iters (640/32).
// R9 (kept): batch->XCD pin (b=blockIdx&15); idx prefetch 2 tiles ahead.
__global__ __launch_bounds__(512, 2) void gemm_max_kernel(
    const unsigned short* __restrict__ p, const unsigned short* __restrict__ q,
    const int* __restrict__ idx, const float* __restrict__ W3, int* __restrict__ H) {
  __shared__ __align__(16) unsigned short h2s[2][64 * 128];  // 32 KB double-buffered

  int b = blockIdx.x & 15;
  int w = blockIdx.x >> 4;            // 0..31
  int t = threadIdx.x;                // 0..511
  int lane = t & 63, wid = t >> 6;    // 8 waves
  int col = lane & 31, hi = lane >> 5;
  int mb = (wid & 4) * 8;             // M-block row base: 0 or 32
  int nb = (wid & 3) * 64;            // channel base: wave owns [nb, nb+64)

  // B fragments: 2 ntiles (nb+col, nb+32+col); k = kk*16 + hi*8 + j
  v8h bfr0[8], bfr1[8];
#pragma unroll
  for (int kk = 0; kk < 8; ++kk) {
    const float* s0 = W3 + (size_t)(nb + col) * 128 + kk * 16 + hi * 8;
    const float* s1 = s0 + 32 * 128;
    v8h f0, f1;
#pragma unroll
    for (int jj = 0; jj < 8; ++jj) { f0[jj] = (_Float16)s0[jj]; f1[jj] = (_Float16)s1[jj]; }
    bfr0[kk] = f0; bfr1[kk] = f1;
  }

  const unsigned short* pB = p + (size_t)b * NPTS * 128;
  const unsigned short* qB = q + (size_t)b * NPTS * 128;
  const int* idxB = idx + (size_t)b * PAIRS;

  int pm = t >> 3;        // pair-in-tile 0..63
  int c2 = t & 7;         // covers 16B units 2*c2, 2*c2+1 (32B of the row)
  // swizzled LDS store offsets (shorts): unit u -> u ^ (row&7)
  int st0 = pm * 128 + (((c2 * 2) ^ (pm & 7)) * 8);
  int st1 = pm * 128 + (((c2 * 2 + 1) ^ (pm & 7)) * 8);

  const int NT = PAIRS / 64;          // 640 tiles/batch; stride 32 -> 20 iters
  int arow = mb + col;                // this lane's A row (arow&7 == col&7)

  // prologue: loads for tile w; idx one tile ahead
  uint4 P0, P1, Q0, Q1;
  int jn = 0;
  {
    int pr = w * 64 + pm;
    int j = idxB[pr] & (NPTS - 1);
    int n = pr / 20;
    P0 = *(const uint4*)(pB + (size_t)j * 128 + c2 * 16);
    P1 = *(const uint4*)(pB + (size_t)j * 128 + c2 * 16 + 8);
    Q0 = *(const uint4*)(qB + (size_t)n * 128 + c2 * 16);
    Q1 = *(const uint4*)(qB + (size_t)n * 128 + c2 * 16 + 8);
    int T1 = w + 32;
    if (T1 < NT) jn = idxB[T1 * 64 + pm];
  }

  float vmx0 = 0.f, vmx1 = 0.f;
  int buf = 0;
  for (int T = w; T < NT; T += 32) {
    // stage h2 tile (64 pairs x 128 ch, fp16) from prefetched regs
    uint4 R0, R1;
    R0.x = pair_relu_h2(P0.x, Q0.x); R0.y = pair_relu_h2(P0.y, Q0.y);
    R0.z = pair_relu_h2(P0.z, Q0.z); R0.w = pair_relu_h2(P0.w, Q0.w);
    R1.x = pair_relu_h2(P1.x, Q1.x); R1.y = pair_relu_h2(P1.y, Q1.y);
    R1.z = pair_relu_h2(P1.z, Q1.z); R1.w = pair_relu_h2(P1.w, Q1.w);
    *(uint4*)&h2s[buf][st0] = R0;
    *(uint4*)&h2s[buf][st1] = R1;
    __syncthreads();   // one barrier/iter: dbuf covers the read-vs-overwrite hazard

    // prefetch tile T+32 (p-row from jn loaded last iter); idx for T+64
    int Tn = T + 32;
    if (Tn < NT) {
      int prn = Tn * 64 + pm;
      int j = jn & (NPTS - 1);
      int n = prn / 20;
      P0 = *(const uint4*)(pB + (size_t)j * 128 + c2 * 16);
      P1 = *(const uint4*)(pB + (size_t)j * 128 + c2 * 16 + 8);
      Q0 = *(const uint4*)(qB + (size_t)n * 128 + c2 * 16);
      Q1 = *(const uint4*)(qB + (size_t)n * 128 + c2 * 16 + 8);
      int T2 = T + 64;
      if (T2 < NT) jn = idxB[T2 * 64 + pm];
    }

    // compute: one a[kk] read feeds both ntiles (16 MFMA per 8 ds_read)
    v16f acc0 = {0.f}, acc1 = {0.f};
#pragma unroll
    for (int kk = 0; kk < 8; ++kk) {
      v8h a = *(const v8h*)&h2s[buf][arow * 128 + (((kk * 2 + hi) ^ (col & 7)) * 8)];
      acc0 = __builtin_amdgcn_mfma_f32_32x32x16_f16(a, bfr0[kk], acc0, 0, 0, 0);
      acc1 = __builtin_amdgcn_mfma_f32_32x32x16_f16(a, bfr1[kk], acc1, 0, 0, 0);
    }
    // relu folds into max (vmx starts at 0); v_max3 triples: 8 ops per acc
    {
      float m0 = fmax3(acc0[0], acc0[1], acc0[2]);
      float m1 = fmax3(acc0[3], acc0[4], acc0[5]);
      float m2 = fmax3(acc0[6], acc0[7], acc0[8]);
      float m3 = fmax3(acc0[9], acc0[10], acc0[11]);
      float m4 = fmax3(acc0[12], acc0[13], acc0[14]);
      vmx0 = fmax3(fmax3(m0, m1, m2), fmax3(m3, m4, acc0[15]), vmx0);
      float n0 = fmax3(acc1[0], acc1[1], acc1[2]);
      float n1 = fmax3(acc1[3], acc1[4], acc1[5]);
      float n2 = fmax3(acc1[6], acc1[7], acc1[8]);
      float n3 = fmax3(acc1[9], acc1[10], acc1[11]);
      float n4 = fmax3(acc1[12], acc1[13], acc1[14]);
      vmx1 = fmax3(fmax3(n0, n1, n2), fmax3(n3, n4, acc1[15]), vmx1);
    }
    buf ^= 1;
  }

  // lanes l and l^32 hold the same channel (complementary rows): reduce, write
  float v0 = fmaxf(vmx0, __shfl_xor(vmx0, 32));
  float v1 = fmaxf(vmx1, __shfl_xor(vmx1, 32));
  if (hi == 0) {
    atomicMax(&H[b * 256 + nb + col], __float_as_int(v0));
    atomicMax(&H[b * 256 + nb + 32 + col], __float_as_int(v1));
  }
}

// ---------- K4: out = H @ fc_w^T + fc_b (one wave per output element) ----------
__global__ __launch_bounds__(64) void fc_kernel(const int* __restrict__ Hi,
                                                const float* __restrict__ fcw,
                                                const float* __restrict__ fcb,
                                                float* __restrict__ out) {
  int b = blockIdx.x / 10, r = blockIdx.x % 10;
  int lane = threadIdx.x;
  const float* Hb = (const float*)Hi + b * 256;
  float s = 0.f;
#pragma unroll
  for (int c = lane; c < 256; c += 64) s += Hb[c] * fcw[r * 256 + c];
#pragma unroll
  for (int m = 32; m > 0; m >>= 1) s += __shfl_xor(s, m);
  if (lane == 0) out[b * 10 + r] = s + fcb[r];
}

// ---------- launch ----------
extern "C" void kernel_launch(void* const* d_in, const int* in_sizes, int n_in,
                              void* d_out, int out_size, void* d_ws, size_t ws_size,
                              hipStream_t stream) {
  const float* x   = (const float*)d_in[0];
  const float* W1  = (const float*)d_in[1];
  const float* W2  = (const float*)d_in[2];
  const float* W3  = (const float*)d_in[3];
  const float* fcw = (const float*)d_in[4];
  const float* fcb = (const float*)d_in[5];
  float* out = (float*)d_out;
  char* ws = (char*)d_ws;

  // workspace layout (needs ~20 MB)
  float* M2a = (float*)(ws + 0);            // 1536 B
  float* M2b = (float*)(ws + 1536);         // 1536 B
  int* H     = (int*)(ws + 4096);           // 16 KB (16x256 f32-as-int)
  int* idx   = (int*)(ws + 24576);          // 2.62 MB
  unsigned short* p = (unsigned short*)(ws + 3145728);   // 8.39 MB fp16
  unsigned short* q = (unsigned short*)(ws + 12582912);  // 8.39 MB fp16

  prep_kernel<<<32, 128, 0, stream>>>(W1, W2, M2a, M2b, H);
  pq_kernel<<<BATCH * 64, 64, 0, stream>>>(x, M2a, M2b, p, q);
  knn_kernel<<<BATCH * 32, 512, 0, stream>>>(x, idx);
  gemm_max_kernel<<<BATCH * 32, 512, 0, stream>>>(p, q, idx, W3, H);
  fc_kernel<<<BATCH * 10, 64, 0, stream>>>(H, fcw, fcb, out);
}

// Round 8
// 166.740 us; speedup vs baseline: 1.1747x; 1.0383x over previous
//
#include <hip/hip_runtime.h>
#include <stdint.h>

typedef _Float16 v8h __attribute__((ext_vector_type(8)));
typedef _Float16 v2h __attribute__((ext_vector_type(2)));
typedef float v4f __attribute__((ext_vector_type(4)));
typedef float v16f __attribute__((ext_vector_type(16)));

#define NPTS 2048
#define BATCH 16
#define KNN 20
#define PAIRS (NPTS * KNN)   // 40960 per batch

// ---------- helpers ----------
// R6/R7: fp16 pair op: 2 packed ops (v_pk_add_f16 + v_pk_max_f16).
__device__ __forceinline__ unsigned pair_relu_h2(unsigned pu, unsigned qu) {
  v2h a = *(const v2h*)&pu;
  v2h b = *(const v2h*)&qu;
  v2h s = a + b;                                   // v_pk_add_f16
  v2h z = {(_Float16)0.f, (_Float16)0.f};
  v2h r = __builtin_elementwise_max(s, z);         // v_pk_max_f16 (relu)
  return *(const unsigned*)&r;
}
// clang fuses fmaxf(fmaxf(a,b),c) -> v_max3_f32 (single VALU op)
__device__ __forceinline__ float fmax3(float a, float b, float c) {
  return fmaxf(fmaxf(a, b), c);
}

// ---------- K0: fold M2a = W2*W1a, M2b = W2*(W1b-W1a); zero H ----------
__global__ void prep_kernel(const float* __restrict__ W1, const float* __restrict__ W2,
                            float* __restrict__ M2a, float* __restrict__ M2b,
                            int* __restrict__ H) {
  if (blockIdx.x == 0 && threadIdx.x < 128) {
    int o = threadIdx.x;
    float a0 = 0, a1 = 0, a2 = 0, b0 = 0, b1 = 0, b2 = 0;
    for (int i = 0; i < 64; ++i) {
      float w2 = W2[o * 64 + i];
      const float* w1r = W1 + i * 6;
      a0 += w2 * w1r[0]; a1 += w2 * w1r[1]; a2 += w2 * w1r[2];
      b0 += w2 * (w1r[3] - w1r[0]); b1 += w2 * (w1r[4] - w1r[1]); b2 += w2 * (w1r[5] - w1r[2]);
    }
    M2a[o * 3 + 0] = a0; M2a[o * 3 + 1] = a1; M2a[o * 3 + 2] = a2;
    M2b[o * 3 + 0] = b0; M2b[o * 3 + 1] = b1; M2b[o * 3 + 2] = b2;
  }
  int g = blockIdx.x * 128 + threadIdx.x;
  if (g < BATCH * 256) H[g] = 0;
}

// ---------- K1: p[b][j][o] = M2a[o]·x_j ; q likewise (fp16, packed pairs) ----------
__global__ __launch_bounds__(64) void pq_kernel(const float* __restrict__ x,
                                                const float* __restrict__ M2a,
                                                const float* __restrict__ M2b,
                                                unsigned short* __restrict__ p,
                                                unsigned short* __restrict__ q) {
  int b = blockIdx.x >> 6;
  int j0 = (blockIdx.x & 63) << 5;
  int t = threadIdx.x;                 // 0..63 -> channels 2t, 2t+1
  int o0 = t * 2;
  float a00 = M2a[o0 * 3 + 0], a01 = M2a[o0 * 3 + 1], a02 = M2a[o0 * 3 + 2];
  float a10 = M2a[o0 * 3 + 3], a11 = M2a[o0 * 3 + 4], a12 = M2a[o0 * 3 + 5];
  float b00 = M2b[o0 * 3 + 0], b01 = M2b[o0 * 3 + 1], b02 = M2b[o0 * 3 + 2];
  float b10 = M2b[o0 * 3 + 3], b11 = M2b[o0 * 3 + 4], b12 = M2b[o0 * 3 + 5];
  const float* xb = x + b * 3 * NPTS;
  unsigned* pw = (unsigned*)p;
  unsigned* qw = (unsigned*)q;
  for (int jj = 0; jj < 32; ++jj) {
    int j = j0 + jj;
    float x0 = xb[j], x1 = xb[NPTS + j], x2 = xb[2 * NPTS + j];
    float p0 = a00 * x0 + a01 * x1 + a02 * x2;
    float p1 = a10 * x0 + a11 * x1 + a12 * x2;
    float q0 = b00 * x0 + b01 * x1 + b02 * x2;
    float q1 = b10 * x0 + b11 * x1 + b12 * x2;
    size_t base = ((size_t)(b * NPTS + j)) * 64 + t;   // dword index
    auto hp = __builtin_amdgcn_cvt_pkrtz(p0, p1);      // v_cvt_pkrtz_f16_f32
    auto hq = __builtin_amdgcn_cvt_pkrtz(q0, q1);
    pw[base] = *(const unsigned*)&hp;
    qw[base] = *(const unsigned*)&hq;
  }
}

// ---------- K2: exact 20-NN ----------
// R10: knn was the top dispatch (53us, VALUBusy 76%, MfmaUtil 0) -> pure
// VALU-inst-count bound. Cuts:
//  (a) norm trick: stage (x,y,z,|x|^2) float4; d' = nrm - 2 q.x via 3 FMA
//      (was 3 sub + 3 fma); 1 ds_read_b128 w/ static offset (was 3 b32).
//      d' = |x-q|^2 - |q|^2 (order-preserving; can be negative -> sort key
//      is float_as_uint(d'+64), monotone since d' > -64 for this data).
//  (b) 8 queries/wave + 512-thr blocks: halves shared overhead & staging;
//      grid 512 = exactly 2 blocks/CU, LDS 64KB -> occupancy 35->50%.
//  (c) 64 cand slots (E[cnt]~23, P(>64) ~6 sigma): single-key rank-count.
//  tau inflation sign-safe for negative d': t + |t|*4e-6 + 1e-6.
__global__ __launch_bounds__(512, 4) void knn_kernel(const float* __restrict__ x,
                                                     int* __restrict__ idxOut) {
  __shared__ float4 pts[NPTS];                    // 32 KB (x,y,z,|.|^2)
  __shared__ unsigned long long cand[8][8][64];   // 32 KB, wave-private
  int b = blockIdx.x >> 5;
  int qblk = blockIdx.x & 31;
  const float* xb = x + b * 3 * NPTS;
  for (int i = threadIdx.x; i < NPTS; i += 512) {
    float X = xb[i], Y = xb[NPTS + i], Z = xb[2 * NPTS + i];
    pts[i] = make_float4(X, Y, Z, X * X + Y * Y + Z * Z);
  }
  __syncthreads();
  int wid = threadIdx.x >> 6, lane = threadIdx.x & 63;
  int qbase = qblk * 64 + wid * 8;                // 8 queries per wave

  float m2x[8], m2y[8], m2z[8], mn[8];
#pragma unroll
  for (int g = 0; g < 8; ++g) {
    float4 qp = pts[qbase + g];                   // broadcast read
    m2x[g] = -2.f * qp.x; m2y[g] = -2.f * qp.y; m2z[g] = -2.f * qp.z;
    mn[g] = 1e30f;
  }

  // pass 1: per-lane min over its 32 points, all 8 queries share the load
  for (int s = 0; s < 32; ++s) {
    float4 P = pts[s * 64 + lane];
#pragma unroll
    for (int g = 0; g < 8; ++g) {
      float d = fmaf(m2x[g], P.x, fmaf(m2y[g], P.y, fmaf(m2z[g], P.z, P.w)));
      mn[g] = fminf(mn[g], d);
    }
  }

  // tau[g] = 20th-smallest lane-min (upper bound on d'_(20)), inflated
  float tau[8];
#pragma unroll
  for (int g = 0; g < 8; ++g) {
    float v = mn[g];
    for (int k = 2; k <= 64; k <<= 1) {
      for (int j = k >> 1; j > 0; j >>= 1) {
        float o = __shfl_xor(v, j);
        bool low = (lane & j) == 0;
        bool up = (lane & k) == 0;
        v = (low == up) ? fminf(v, o) : fmaxf(v, o);
      }
    }
    float t = __shfl(v, 19);
    tau[g] = t + fabsf(t) * 4e-6f + 1e-6f;
  }

  // pass 2: recompute, ballot-compact candidates per query
  int cnt[8] = {0, 0, 0, 0, 0, 0, 0, 0};
  for (int s = 0; s < 32; ++s) {
    int i = s * 64 + lane;
    float4 P = pts[i];
#pragma unroll
    for (int g = 0; g < 8; ++g) {
      float d = fmaf(m2x[g], P.x, fmaf(m2y[g], P.y, fmaf(m2z[g], P.z, P.w)));
      bool take = d <= tau[g];
      unsigned long long mb = __ballot(take);
      if (take) {
        int pos = cnt[g] + __popcll(mb & ((1ull << lane) - 1ull));
        if (pos < 64) {
          unsigned kd = __float_as_uint(d + 64.f);   // d > -64: monotone key
          cand[wid][g][pos] = (((unsigned long long)kd) << 32) | (unsigned)i;
        }
      }
      cnt[g] += __popcll(mb);
    }
  }
  // cand written & read by the same wave: no __syncthreads needed.

  // rank-count select: broadcast reads (same addr all lanes = free).
  // Keys unique (index tiebreak) -> exact ranks; >=20 candidates guaranteed
  // (>=20 lanes have lane-min <= tau, each contributes >=1).
#pragma unroll
  for (int g = 0; g < 8; ++g) {
    int nc = cnt[g] < 64 ? cnt[g] : 64;
    unsigned long long k0 = (lane < nc) ? cand[wid][g][lane] : ~0ull;
    int r0 = 0;
    for (int i = 0; i < nc; ++i) r0 += (cand[wid][g][i] < k0) ? 1 : 0;
    long long obase = ((long long)b * NPTS + qbase + g) * KNN;
    if (lane < nc && r0 < KNN) idxOut[obase + r0] = (int)(k0 & 0xffffffffu);
  }
}

// ---------- K3: h3 = relu(W3 · relu(p_j+q_n)) via MFMA, fused max-reduce ----------
// R13: R10 structure verbatim (measured 51.4us, MfmaUtil 33) with grid
// 48->64 w-blocks: 4 blocks/CU x 4 waves = 16 waves/CU = the HW cap for
// VGPR>64 (m69 granule: 84 VGPR -> 4 waves/SIMD). 4 independent barrier
// groups/CU (R12's 512-thr/2-group variant regressed to 60us). Stride 64
// -> 20 exact iters, uniform branches. __launch_bounds__(256,3) NOT (256,4):
// R11's (256,4) forced a 64-VGPR cap -> acc/bfr spill -> 48MB HBM writes.
// Tripwire: VGPR_Count must stay ~84; if 64, void the round.
// R9 (kept): batch->XCD pin (b=blockIdx&15); 2 ntiles per a[kk] read; idx
// prefetched 2 tiles ahead, p/q 1 ahead; swizzled conflict-free LDS.
__global__ __launch_bounds__(256, 3) void gemm_max_kernel(
    const unsigned short* __restrict__ p, const unsigned short* __restrict__ q,
    const int* __restrict__ idx, const float* __restrict__ W3, int* __restrict__ H) {
  __shared__ __align__(16) unsigned short h2s[2][32 * 128];  // 16 KB double-buffered

  int b = blockIdx.x & 15;
  int w = blockIdx.x >> 4;            // 0..63
  int t = threadIdx.x;                // 0..255
  int lane = t & 63, wid = t >> 6;    // 4 waves
  int col = lane & 31, hi = lane >> 5;

  // B fragments: wave owns channels [wid*64, wid*64+64) as 2 ntiles.
  // B[k][n]: lane holds n = ntl-base + col, k = kk*16 + hi*8 + j.
  v8h bfr0[8], bfr1[8];
#pragma unroll
  for (int kk = 0; kk < 8; ++kk) {
    const float* s0 = W3 + (size_t)(wid * 64 + col) * 128 + kk * 16 + hi * 8;
    const float* s1 = s0 + 32 * 128;
    v8h f0, f1;
#pragma unroll
    for (int jj = 0; jj < 8; ++jj) { f0[jj] = (_Float16)s0[jj]; f1[jj] = (_Float16)s1[jj]; }
    bfr0[kk] = f0; bfr1[kk] = f1;
  }

  const unsigned short* pB = p + (size_t)b * NPTS * 128;
  const unsigned short* qB = q + (size_t)b * NPTS * 128;
  const int* idxB = idx + (size_t)b * PAIRS;

  int pm = t >> 3;        // pair-in-tile 0..31
  int c2 = t & 7;         // covers 16B units 2*c2, 2*c2+1 (32B of the row)
  // swizzled LDS store offsets (shorts): unit u -> u ^ (row&7)
  int st0 = pm * 128 + (((c2 * 2) ^ (pm & 7)) * 8);
  int st1 = pm * 128 + (((c2 * 2 + 1) ^ (pm & 7)) * 8);

  const int NT = PAIRS / 32;          // 1280 tiles/batch; stride 64 -> 20 iters

  // prologue: loads for tile w; idx one tile ahead
  uint4 P0, P1, Q0, Q1;
  int jn = 0;
  {
    int pr = w * 32 + pm;
    int j = idxB[pr] & (NPTS - 1);
    int n = pr / 20;
    P0 = *(const uint4*)(pB + (size_t)j * 128 + c2 * 16);
    P1 = *(const uint4*)(pB + (size_t)j * 128 + c2 * 16 + 8);
    Q0 = *(const uint4*)(qB + (size_t)n * 128 + c2 * 16);
    Q1 = *(const uint4*)(qB + (size_t)n * 128 + c2 * 16 + 8);
    int T1 = w + 64;
    if (T1 < NT) jn = idxB[T1 * 32 + pm];
  }

  float vmx0 = 0.f, vmx1 = 0.f;
  int buf = 0;
  for (int T = w; T < NT; T += 64) {
    // stage h2 tile (32 pairs x 128 ch, fp16) from prefetched regs
    uint4 R0, R1;
    R0.x = pair_relu_h2(P0.x, Q0.x); R0.y = pair_relu_h2(P0.y, Q0.y);
    R0.z = pair_relu_h2(P0.z, Q0.z); R0.w = pair_relu_h2(P0.w, Q0.w);
    R1.x = pair_relu_h2(P1.x, Q1.x); R1.y = pair_relu_h2(P1.y, Q1.y);
    R1.z = pair_relu_h2(P1.z, Q1.z); R1.w = pair_relu_h2(P1.w, Q1.w);
    *(uint4*)&h2s[buf][st0] = R0;
    *(uint4*)&h2s[buf][st1] = R1;
    __syncthreads();   // one barrier/iter: dbuf covers the read-vs-overwrite hazard

    // prefetch tile T+64 (p-row from jn loaded last iter); idx for T+128
    int Tn = T + 64;
    if (Tn < NT) {
      int prn = Tn * 32 + pm;
      int j = jn & (NPTS - 1);
      int n = prn / 20;
      P0 = *(const uint4*)(pB + (size_t)j * 128 + c2 * 16);
      P1 = *(const uint4*)(pB + (size_t)j * 128 + c2 * 16 + 8);
      Q0 = *(const uint4*)(qB + (size_t)n * 128 + c2 * 16);
      Q1 = *(const uint4*)(qB + (size_t)n * 128 + c2 * 16 + 8);
      int T2 = T + 128;
      if (T2 < NT) jn = idxB[T2 * 32 + pm];
    }

    // compute: one a[kk] read feeds both ntiles (16 MFMA per 8 ds_read)
    v16f acc0 = {0.f}, acc1 = {0.f};
#pragma unroll
    for (int kk = 0; kk < 8; ++kk) {
      v8h a = *(const v8h*)&h2s[buf][col * 128 + (((kk * 2 + hi) ^ (col & 7)) * 8)];
      acc0 = __builtin_amdgcn_mfma_f32_32x32x16_f16(a, bfr0[kk], acc0, 0, 0, 0);
      acc1 = __builtin_amdgcn_mfma_f32_32x32x16_f16(a, bfr1[kk], acc1, 0, 0, 0);
    }
    // relu folds into max (vmx starts at 0); v_max3 triples: 8 ops per acc
    {
      float m0 = fmax3(acc0[0], acc0[1], acc0[2]);
      float m1 = fmax3(acc0[3], acc0[4], acc0[5]);
      float m2 = fmax3(acc0[6], acc0[7], acc0[8]);
      float m3 = fmax3(acc0[9], acc0[10], acc0[11]);
      float m4 = fmax3(acc0[12], acc0[13], acc0[14]);
      vmx0 = fmax3(fmax3(m0, m1, m2), fmax3(m3, m4, acc0[15]), vmx0);
      float n0 = fmax3(acc1[0], acc1[1], acc1[2]);
      float n1 = fmax3(acc1[3], acc1[4], acc1[5]);
      float n2 = fmax3(acc1[6], acc1[7], acc1[8]);
      float n3 = fmax3(acc1[9], acc1[10], acc1[11]);
      float n4 = fmax3(acc1[12], acc1[13], acc1[14]);
      vmx1 = fmax3(fmax3(n0, n1, n2), fmax3(n3, n4, acc1[15]), vmx1);
    }
    buf ^= 1;
  }

  // lanes l and l^32 hold the same channel (complementary rows): reduce, write
  float v0 = fmaxf(vmx0, __shfl_xor(vmx0, 32));
  float v1 = fmaxf(vmx1, __shfl_xor(vmx1, 32));
  if (hi == 0) {
    atomicMax(&H[b * 256 + wid * 64 + col], __float_as_int(v0));
    atomicMax(&H[b * 256 + wid * 64 + 32 + col], __float_as_int(v1));
  }
}

// ---------- K4: out = H @ fc_w^T + fc_b (one wave per output element) ----------
__global__ __launch_bounds__(64) void fc_kernel(const int* __restrict__ Hi,
                                                const float* __restrict__ fcw,
                                                const float* __restrict__ fcb,
                                                float* __restrict__ out) {
  int b = blockIdx.x / 10, r = blockIdx.x % 10;
  int lane = threadIdx.x;
  const float* Hb = (const float*)Hi + b * 256;
  float s = 0.f;
#pragma unroll
  for (int c = lane; c < 256; c += 64) s += Hb[c] * fcw[r * 256 + c];
#pragma unroll
  for (int m = 32; m > 0; m >>= 1) s += __shfl_xor(s, m);
  if (lane == 0) out[b * 10 + r] = s + fcb[r];
}

// ---------- launch ----------
extern "C" void kernel_launch(void* const* d_in, const int* in_sizes, int n_in,
                              void* d_out, int out_size, void* d_ws, size_t ws_size,
                              hipStream_t stream) {
  const float* x   = (const float*)d_in[0];
  const float* W1  = (const float*)d_in[1];
  const float* W2  = (const float*)d_in[2];
  const float* W3  = (const float*)d_in[3];
  const float* fcw = (const float*)d_in[4];
  const float* fcb = (const float*)d_in[5];
  float* out = (float*)d_out;
  char* ws = (char*)d_ws;

  // workspace layout (needs ~20 MB)
  float* M2a = (float*)(ws + 0);            // 1536 B
  float* M2b = (float*)(ws + 1536);         // 1536 B
  int* H     = (int*)(ws + 4096);           // 16 KB (16x256 f32-as-int)
  int* idx   = (int*)(ws + 24576);          // 2.62 MB
  unsigned short* p = (unsigned short*)(ws + 3145728);   // 8.39 MB fp16
  unsigned short* q = (unsigned short*)(ws + 12582912);  // 8.39 MB fp16

  prep_kernel<<<32, 128, 0, stream>>>(W1, W2, M2a, M2b, H);
  pq_kernel<<<BATCH * 64, 64, 0, stream>>>(x, M2a, M2b, p, q);
  knn_kernel<<<BATCH * 32, 512, 0, stream>>>(x, idx);
  gemm_max_kernel<<<BATCH * 64, 256, 0, stream>>>(p, q, idx, W3, H);
  fc_kernel<<<BATCH * 10, 64, 0, stream>>>(H, fcw, fcb, out);
}

// Round 9
// 162.067 us; speedup vs baseline: 1.2085x; 1.0288x over previous
//
#include <hip/hip_runtime.h>
#include <stdint.h>

typedef _Float16 v8h __attribute__((ext_vector_type(8)));
typedef _Float16 v2h __attribute__((ext_vector_type(2)));
typedef float v4f __attribute__((ext_vector_type(4)));
typedef float v16f __attribute__((ext_vector_type(16)));

#define NPTS 2048
#define BATCH 16
#define KNN 20
#define PAIRS (NPTS * KNN)   // 40960 per batch

// ---------- helpers ----------
// R6/R7: fp16 pair op: 2 packed ops (v_pk_add_f16 + v_pk_max_f16).
__device__ __forceinline__ unsigned pair_relu_h2(unsigned pu, unsigned qu) {
  v2h a = *(const v2h*)&pu;
  v2h b = *(const v2h*)&qu;
  v2h s = a + b;                                   // v_pk_add_f16
  v2h z = {(_Float16)0.f, (_Float16)0.f};
  v2h r = __builtin_elementwise_max(s, z);         // v_pk_max_f16 (relu)
  return *(const unsigned*)&r;
}
// clang fuses fmaxf(fmaxf(a,b),c) -> v_max3_f32 (single VALU op)
__device__ __forceinline__ float fmax3(float a, float b, float c) {
  return fmaxf(fmaxf(a, b), c);
}

// ---------- K0: fold M2a = W2*W1a, M2b = W2*(W1b-W1a); zero H ----------
__global__ void prep_kernel(const float* __restrict__ W1, const float* __restrict__ W2,
                            float* __restrict__ M2a, float* __restrict__ M2b,
                            int* __restrict__ H) {
  if (blockIdx.x == 0 && threadIdx.x < 128) {
    int o = threadIdx.x;
    float a0 = 0, a1 = 0, a2 = 0, b0 = 0, b1 = 0, b2 = 0;
    for (int i = 0; i < 64; ++i) {
      float w2 = W2[o * 64 + i];
      const float* w1r = W1 + i * 6;
      a0 += w2 * w1r[0]; a1 += w2 * w1r[1]; a2 += w2 * w1r[2];
      b0 += w2 * (w1r[3] - w1r[0]); b1 += w2 * (w1r[4] - w1r[1]); b2 += w2 * (w1r[5] - w1r[2]);
    }
    M2a[o * 3 + 0] = a0; M2a[o * 3 + 1] = a1; M2a[o * 3 + 2] = a2;
    M2b[o * 3 + 0] = b0; M2b[o * 3 + 1] = b1; M2b[o * 3 + 2] = b2;
  }
  int g = blockIdx.x * 128 + threadIdx.x;
  if (g < BATCH * 256) H[g] = 0;
}

// ---------- K1: p[b][j][o] = M2a[o]·x_j ; q likewise (fp16, packed pairs) ----------
__global__ __launch_bounds__(64) void pq_kernel(const float* __restrict__ x,
                                                const float* __restrict__ M2a,
                                                const float* __restrict__ M2b,
                                                unsigned short* __restrict__ p,
                                                unsigned short* __restrict__ q) {
  int b = blockIdx.x >> 6;
  int j0 = (blockIdx.x & 63) << 5;
  int t = threadIdx.x;                 // 0..63 -> channels 2t, 2t+1
  int o0 = t * 2;
  float a00 = M2a[o0 * 3 + 0], a01 = M2a[o0 * 3 + 1], a02 = M2a[o0 * 3 + 2];
  float a10 = M2a[o0 * 3 + 3], a11 = M2a[o0 * 3 + 4], a12 = M2a[o0 * 3 + 5];
  float b00 = M2b[o0 * 3 + 0], b01 = M2b[o0 * 3 + 1], b02 = M2b[o0 * 3 + 2];
  float b10 = M2b[o0 * 3 + 3], b11 = M2b[o0 * 3 + 4], b12 = M2b[o0 * 3 + 5];
  const float* xb = x + b * 3 * NPTS;
  unsigned* pw = (unsigned*)p;
  unsigned* qw = (unsigned*)q;
  for (int jj = 0; jj < 32; ++jj) {
    int j = j0 + jj;
    float x0 = xb[j], x1 = xb[NPTS + j], x2 = xb[2 * NPTS + j];
    float p0 = a00 * x0 + a01 * x1 + a02 * x2;
    float p1 = a10 * x0 + a11 * x1 + a12 * x2;
    float q0 = b00 * x0 + b01 * x1 + b02 * x2;
    float q1 = b10 * x0 + b11 * x1 + b12 * x2;
    size_t base = ((size_t)(b * NPTS + j)) * 64 + t;   // dword index
    auto hp = __builtin_amdgcn_cvt_pkrtz(p0, p1);      // v_cvt_pkrtz_f16_f32
    auto hq = __builtin_amdgcn_cvt_pkrtz(q0, q1);
    pw[base] = *(const unsigned*)&hp;
    qw[base] = *(const unsigned*)&hq;
  }
}

// ---------- K2: exact 20-NN ----------
// R10: knn was the top dispatch (53us, VALUBusy 76%, MfmaUtil 0) -> pure
// VALU-inst-count bound. Cuts:
//  (a) norm trick: stage (x,y,z,|x|^2) float4; d' = nrm - 2 q.x via 3 FMA
//      (was 3 sub + 3 fma); 1 ds_read_b128 w/ static offset (was 3 b32).
//      d' = |x-q|^2 - |q|^2 (order-preserving; can be negative -> sort key
//      is float_as_uint(d'+64), monotone since d' > -64 for this data).
//  (b) 8 queries/wave + 512-thr blocks: halves shared overhead & staging;
//      grid 512 = exactly 2 blocks/CU, LDS 64KB -> occupancy 35->50%.
//  (c) 64 cand slots (E[cnt]~23, P(>64) ~6 sigma): single-key rank-count.
//  tau inflation sign-safe for negative d': t + |t|*4e-6 + 1e-6.
__global__ __launch_bounds__(512, 4) void knn_kernel(const float* __restrict__ x,
                                                     int* __restrict__ idxOut) {
  __shared__ float4 pts[NPTS];                    // 32 KB (x,y,z,|.|^2)
  __shared__ unsigned long long cand[8][8][64];   // 32 KB, wave-private
  int b = blockIdx.x >> 5;
  int qblk = blockIdx.x & 31;
  const float* xb = x + b * 3 * NPTS;
  for (int i = threadIdx.x; i < NPTS; i += 512) {
    float X = xb[i], Y = xb[NPTS + i], Z = xb[2 * NPTS + i];
    pts[i] = make_float4(X, Y, Z, X * X + Y * Y + Z * Z);
  }
  __syncthreads();
  int wid = threadIdx.x >> 6, lane = threadIdx.x & 63;
  int qbase = qblk * 64 + wid * 8;                // 8 queries per wave

  float m2x[8], m2y[8], m2z[8], mn[8];
#pragma unroll
  for (int g = 0; g < 8; ++g) {
    float4 qp = pts[qbase + g];                   // broadcast read
    m2x[g] = -2.f * qp.x; m2y[g] = -2.f * qp.y; m2z[g] = -2.f * qp.z;
    mn[g] = 1e30f;
  }

  // pass 1: per-lane min over its 32 points, all 8 queries share the load
  for (int s = 0; s < 32; ++s) {
    float4 P = pts[s * 64 + lane];
#pragma unroll
    for (int g = 0; g < 8; ++g) {
      float d = fmaf(m2x[g], P.x, fmaf(m2y[g], P.y, fmaf(m2z[g], P.z, P.w)));
      mn[g] = fminf(mn[g], d);
    }
  }

  // tau[g] = 20th-smallest lane-min (upper bound on d'_(20)), inflated
  float tau[8];
#pragma unroll
  for (int g = 0; g < 8; ++g) {
    float v = mn[g];
    for (int k = 2; k <= 64; k <<= 1) {
      for (int j = k >> 1; j > 0; j >>= 1) {
        float o = __shfl_xor(v, j);
        bool low = (lane & j) == 0;
        bool up = (lane & k) == 0;
        v = (low == up) ? fminf(v, o) : fmaxf(v, o);
      }
    }
    float t = __shfl(v, 19);
    tau[g] = t + fabsf(t) * 4e-6f + 1e-6f;
  }

  // pass 2: recompute, ballot-compact candidates per query
  int cnt[8] = {0, 0, 0, 0, 0, 0, 0, 0};
  for (int s = 0; s < 32; ++s) {
    int i = s * 64 + lane;
    float4 P = pts[i];
#pragma unroll
    for (int g = 0; g < 8; ++g) {
      float d = fmaf(m2x[g], P.x, fmaf(m2y[g], P.y, fmaf(m2z[g], P.z, P.w)));
      bool take = d <= tau[g];
      unsigned long long mb = __ballot(take);
      if (take) {
        int pos = cnt[g] + __popcll(mb & ((1ull << lane) - 1ull));
        if (pos < 64) {
          unsigned kd = __float_as_uint(d + 64.f);   // d > -64: monotone key
          cand[wid][g][pos] = (((unsigned long long)kd) << 32) | (unsigned)i;
        }
      }
      cnt[g] += __popcll(mb);
    }
  }
  // cand written & read by the same wave: no __syncthreads needed.

  // rank-count select: broadcast reads (same addr all lanes = free).
  // Keys unique (index tiebreak) -> exact ranks; >=20 candidates guaranteed
  // (>=20 lanes have lane-min <= tau, each contributes >=1).
#pragma unroll
  for (int g = 0; g < 8; ++g) {
    int nc = cnt[g] < 64 ? cnt[g] : 64;
    unsigned long long k0 = (lane < nc) ? cand[wid][g][lane] : ~0ull;
    int r0 = 0;
    for (int i = 0; i < nc; ++i) r0 += (cand[wid][g][i] < k0) ? 1 : 0;
    long long obase = ((long long)b * NPTS + qbase + g) * KNN;
    if (lane < nc && r0 < KNN) idxOut[obase + r0] = (int)(k0 & 0xffffffffu);
  }
}

// ---------- K3: h3 = relu(W3 · relu(p_j+q_n)) via MFMA, fused max-reduce ----------
// R14: MfmaUtil pinned at 33% across 3/4 blk/CU and 512-thr configs -> the
// binding term is per-iteration serialization (stage->barrier->read->MFMA,
// ~1.1K cyc overhead per 512 MFMA cyc), not residency. Fix: TWO tiles per
// barrier. LDS = 2 dbuf x 2 tiles x 8KB = 32KB. Stage both tiles, ONE
// barrier, prefetch both next tiles (more MLP), 32 MFMAs. Stride 128 ->
// 10 exact iters. +16 VGPR (2nd prefetch quad) stays in the 128-granule:
// same 4 waves/SIMD. Tripwire: VGPR>128 or WRITE_SIZE>>1MB = spill, void.
// R11 lesson kept: launch_bounds (256,3) (cap 170), NEVER (256,4).
// R9 (kept): batch->XCD pin (b=blockIdx&15); 2 ntiles per a[kk] read; idx
// prefetched 2 iterations ahead; swizzled LDS (store/read both peak-rate).
__global__ __launch_bounds__(256, 3) void gemm_max_kernel(
    const unsigned short* __restrict__ p, const unsigned short* __restrict__ q,
    const int* __restrict__ idx, const float* __restrict__ W3, int* __restrict__ H) {
  __shared__ __align__(16) unsigned short h2s[2][2][32 * 128];  // 32 KB: dbuf x 2 tiles

  int b = blockIdx.x & 15;
  int w = blockIdx.x >> 4;            // 0..63
  int t = threadIdx.x;                // 0..255
  int lane = t & 63, wid = t >> 6;    // 4 waves
  int col = lane & 31, hi = lane >> 5;

  // B fragments: wave owns channels [wid*64, wid*64+64) as 2 ntiles.
  // B[k][n]: lane holds n = ntl-base + col, k = kk*16 + hi*8 + j.
  v8h bfr0[8], bfr1[8];
#pragma unroll
  for (int kk = 0; kk < 8; ++kk) {
    const float* s0 = W3 + (size_t)(wid * 64 + col) * 128 + kk * 16 + hi * 8;
    const float* s1 = s0 + 32 * 128;
    v8h f0, f1;
#pragma unroll
    for (int jj = 0; jj < 8; ++jj) { f0[jj] = (_Float16)s0[jj]; f1[jj] = (_Float16)s1[jj]; }
    bfr0[kk] = f0; bfr1[kk] = f1;
  }

  const unsigned short* pB = p + (size_t)b * NPTS * 128;
  const unsigned short* qB = q + (size_t)b * NPTS * 128;
  const int* idxB = idx + (size_t)b * PAIRS;

  int pm = t >> 3;        // pair-in-tile 0..31
  int c2 = t & 7;         // covers 16B units 2*c2, 2*c2+1 (32B of the row)
  // swizzled LDS store offsets (shorts): unit u -> u ^ (row&7)
  int st0 = pm * 128 + (((c2 * 2) ^ (pm & 7)) * 8);
  int st1 = pm * 128 + (((c2 * 2 + 1) ^ (pm & 7)) * 8);

  const int NT = PAIRS / 32;          // 1280 tiles; iter = tiles {T, T+64}, T += 128

  // prologue: loads for tiles w (A) and w+64 (B); idx for w+128 / w+192
  uint4 PA0, PA1, QA0, QA1, PB0, PB1, QB0, QB1;
  int jnA, jnB;
  {
    int prA = w * 32 + pm, prB = (w + 64) * 32 + pm;
    int jA = idxB[prA] & (NPTS - 1);
    int jB = idxB[prB] & (NPTS - 1);
    int nA = prA / 20, nB = prB / 20;
    PA0 = *(const uint4*)(pB + (size_t)jA * 128 + c2 * 16);
    PA1 = *(const uint4*)(pB + (size_t)jA * 128 + c2 * 16 + 8);
    QA0 = *(const uint4*)(qB + (size_t)nA * 128 + c2 * 16);
    QA1 = *(const uint4*)(qB + (size_t)nA * 128 + c2 * 16 + 8);
    PB0 = *(const uint4*)(pB + (size_t)jB * 128 + c2 * 16);
    PB1 = *(const uint4*)(pB + (size_t)jB * 128 + c2 * 16 + 8);
    QB0 = *(const uint4*)(qB + (size_t)nB * 128 + c2 * 16);
    QB1 = *(const uint4*)(qB + (size_t)nB * 128 + c2 * 16 + 8);
    jnA = idxB[(w + 128) * 32 + pm];   // w+128 < 1280 always (w < 64)
    jnB = idxB[(w + 192) * 32 + pm];   // w+192 < 1280 always
  }

  float vmx0 = 0.f, vmx1 = 0.f;
  int buf = 0;
  for (int T = w; T < NT; T += 128) {   // 10 exact iterations
    // stage BOTH tiles from prefetched regs, then ONE barrier
    uint4 R;
    R.x = pair_relu_h2(PA0.x, QA0.x); R.y = pair_relu_h2(PA0.y, QA0.y);
    R.z = pair_relu_h2(PA0.z, QA0.z); R.w = pair_relu_h2(PA0.w, QA0.w);
    *(uint4*)&h2s[buf][0][st0] = R;
    R.x = pair_relu_h2(PA1.x, QA1.x); R.y = pair_relu_h2(PA1.y, QA1.y);
    R.z = pair_relu_h2(PA1.z, QA1.z); R.w = pair_relu_h2(PA1.w, QA1.w);
    *(uint4*)&h2s[buf][0][st1] = R;
    R.x = pair_relu_h2(PB0.x, QB0.x); R.y = pair_relu_h2(PB0.y, QB0.y);
    R.z = pair_relu_h2(PB0.z, QB0.z); R.w = pair_relu_h2(PB0.w, QB0.w);
    *(uint4*)&h2s[buf][1][st0] = R;
    R.x = pair_relu_h2(PB1.x, QB1.x); R.y = pair_relu_h2(PB1.y, QB1.y);
    R.z = pair_relu_h2(PB1.z, QB1.z); R.w = pair_relu_h2(PB1.w, QB1.w);
    *(uint4*)&h2s[buf][1][st1] = R;
    __syncthreads();   // dbuf covers write-after-read across iterations

    // prefetch both tiles of iteration T+128; idx for T+256/T+320
    int Tn = T + 128;
    if (Tn < NT) {
      int prA = Tn * 32 + pm, prB = (Tn + 64) * 32 + pm;
      int jA = jnA & (NPTS - 1), jB = jnB & (NPTS - 1);
      int nA = prA / 20, nB = prB / 20;
      PA0 = *(const uint4*)(pB + (size_t)jA * 128 + c2 * 16);
      PA1 = *(const uint4*)(pB + (size_t)jA * 128 + c2 * 16 + 8);
      QA0 = *(const uint4*)(qB + (size_t)nA * 128 + c2 * 16);
      QA1 = *(const uint4*)(qB + (size_t)nA * 128 + c2 * 16 + 8);
      PB0 = *(const uint4*)(pB + (size_t)jB * 128 + c2 * 16);
      PB1 = *(const uint4*)(pB + (size_t)jB * 128 + c2 * 16 + 8);
      QB0 = *(const uint4*)(qB + (size_t)nB * 128 + c2 * 16);
      QB1 = *(const uint4*)(qB + (size_t)nB * 128 + c2 * 16 + 8);
      int T2 = T + 256;
      if (T2 < NT) {
        jnA = idxB[T2 * 32 + pm];
        jnB = idxB[(T2 + 64) * 32 + pm];
      }
    }

    // compute tile A: one a[kk] read feeds both ntiles (16 MFMA / 8 ds_read)
    {
      v16f acc0 = {0.f}, acc1 = {0.f};
#pragma unroll
      for (int kk = 0; kk < 8; ++kk) {
        v8h a = *(const v8h*)&h2s[buf][0][col * 128 + (((kk * 2 + hi) ^ (col & 7)) * 8)];
        acc0 = __builtin_amdgcn_mfma_f32_32x32x16_f16(a, bfr0[kk], acc0, 0, 0, 0);
        acc1 = __builtin_amdgcn_mfma_f32_32x32x16_f16(a, bfr1[kk], acc1, 0, 0, 0);
      }
      float m0 = fmax3(acc0[0], acc0[1], acc0[2]);
      float m1 = fmax3(acc0[3], acc0[4], acc0[5]);
      float m2 = fmax3(acc0[6], acc0[7], acc0[8]);
      float m3 = fmax3(acc0[9], acc0[10], acc0[11]);
      float m4 = fmax3(acc0[12], acc0[13], acc0[14]);
      vmx0 = fmax3(fmax3(m0, m1, m2), fmax3(m3, m4, acc0[15]), vmx0);
      float n0 = fmax3(acc1[0], acc1[1], acc1[2]);
      float n1 = fmax3(acc1[3], acc1[4], acc1[5]);
      float n2 = fmax3(acc1[6], acc1[7], acc1[8]);
      float n3 = fmax3(acc1[9], acc1[10], acc1[11]);
      float n4 = fmax3(acc1[12], acc1[13], acc1[14]);
      vmx1 = fmax3(fmax3(n0, n1, n2), fmax3(n3, n4, acc1[15]), vmx1);
    }
    // compute tile B
    {
      v16f acc0 = {0.f}, acc1 = {0.f};
#pragma unroll
      for (int kk = 0; kk < 8; ++kk) {
        v8h a = *(const v8h*)&h2s[buf][1][col * 128 + (((kk * 2 + hi) ^ (col & 7)) * 8)];
        acc0 = __builtin_amdgcn_mfma_f32_32x32x16_f16(a, bfr0[kk], acc0, 0, 0, 0);
        acc1 = __builtin_amdgcn_mfma_f32_32x32x16_f16(a, bfr1[kk], acc1, 0, 0, 0);
      }
      float m0 = fmax3(acc0[0], acc0[1], acc0[2]);
      float m1 = fmax3(acc0[3], acc0[4], acc0[5]);
      float m2 = fmax3(acc0[6], acc0[7], acc0[8]);
      float m3 = fmax3(acc0[9], acc0[10], acc0[11]);
      float m4 = fmax3(acc0[12], acc0[13], acc0[14]);
      vmx0 = fmax3(fmax3(m0, m1, m2), fmax3(m3, m4, acc0[15]), vmx0);
      float n0 = fmax3(acc1[0], acc1[1], acc1[2]);
      float n1 = fmax3(acc1[3], acc1[4], acc1[5]);
      float n2 = fmax3(acc1[6], acc1[7], acc1[8]);
      float n3 = fmax3(acc1[9], acc1[10], acc1[11]);
      float n4 = fmax3(acc1[12], acc1[13], acc1[14]);
      vmx1 = fmax3(fmax3(n0, n1, n2), fmax3(n3, n4, acc1[15]), vmx1);
    }
    buf ^= 1;
  }

  // lanes l and l^32 hold the same channel (complementary rows): reduce, write
  float v0 = fmaxf(vmx0, __shfl_xor(vmx0, 32));
  float v1 = fmaxf(vmx1, __shfl_xor(vmx1, 32));
  if (hi == 0) {
    atomicMax(&H[b * 256 + wid * 64 + col], __float_as_int(v0));
    atomicMax(&H[b * 256 + wid * 64 + 32 + col], __float_as_int(v1));
  }
}

// ---------- K4: out = H @ fc_w^T + fc_b (one wave per output element) ----------
__global__ __launch_bounds__(64) void fc_kernel(const int* __restrict__ Hi,
                                                const float* __restrict__ fcw,
                                                const float* __restrict__ fcb,
                                                float* __restrict__ out) {
  int b = blockIdx.x / 10, r = blockIdx.x % 10;
  int lane = threadIdx.x;
  const float* Hb = (const float*)Hi + b * 256;
  float s = 0.f;
#pragma unroll
  for (int c = lane; c < 256; c += 64) s += Hb[c] * fcw[r * 256 + c];
#pragma unroll
  for (int m = 32; m > 0; m >>= 1) s += __shfl_xor(s, m);
  if (lane == 0) out[b * 10 + r] = s + fcb[r];
}

// ---------- launch ----------
extern "C" void kernel_launch(void* const* d_in, const int* in_sizes, int n_in,
                              void* d_out, int out_size, void* d_ws, size_t ws_size,
                              hipStream_t stream) {
  const float* x   = (const float*)d_in[0];
  const float* W1  = (const float*)d_in[1];
  const float* W2  = (const float*)d_in[2];
  const float* W3  = (const float*)d_in[3];
  const float* fcw = (const float*)d_in[4];
  const float* fcb = (const float*)d_in[5];
  float* out = (float*)d_out;
  char* ws = (char*)d_ws;

  // workspace layout (needs ~20 MB)
  float* M2a = (float*)(ws + 0);            // 1536 B
  float* M2b = (float*)(ws + 1536);         // 1536 B
  int* H     = (int*)(ws + 4096);           // 16 KB (16x256 f32-as-int)
  int* idx   = (int*)(ws + 24576);          // 2.62 MB
  unsigned short* p = (unsigned short*)(ws + 3145728);   // 8.39 MB fp16
  unsigned short* q = (unsigned short*)(ws + 12582912);  // 8.39 MB fp16

  prep_kernel<<<32, 128, 0, stream>>>(W1, W2, M2a, M2b, H);
  pq_kernel<<<BATCH * 64, 64, 0, stream>>>(x, M2a, M2b, p, q);
  knn_kernel<<<BATCH * 32, 512, 0, stream>>>(x, idx);
  gemm_max_kernel<<<BATCH * 64, 256, 0, stream>>>(p, q, idx, W3, H);
  fc_kernel<<<BATCH * 10, 64, 0, stream>>>(H, fcw, fcb, out);
}